// Round 17
// baseline (364.253 us; speedup 1.0000x reference)
//
#include <hip/hip_runtime.h>
#include <math.h>

#define NB 512
#define NL 336
#define NC 321
#define NS 28
#define NW 12
#define NH 25
#define NP 8
#define NG 100
#define NT (NS + NP - 1)  // 35 cell steps
#define BSL 16            // batches per wave (1 MFMA column-tile)
#define WPB 4             // independent waves per 256-thread block
#define LOG2E 1.44269504088896340736f
#define N2LOG2E -2.88539008177792681472f

typedef __attribute__((ext_vector_type(8))) _Float16 f16x8;
typedef __attribute__((ext_vector_type(4))) float f32x4;

union F8 { f16x8 v; _Float16 h[8]; };

// q==3 lane carries the extra K-slots: k25=xt, k26=1.0 (A=bias row), k27..31=0
__device__ __forceinline__ void set_q3f(F8& b, bool q3, float xt) {
    b.h[1] = q3 ? (_Float16)xt : b.h[1];
    b.h[2] = q3 ? (_Float16)1.0f : b.h[2];
    b.h[3] = q3 ? (_Float16)0.0f : b.h[3];
    b.h[4] = q3 ? (_Float16)0.0f : b.h[4];
    b.h[5] = q3 ? (_Float16)0.0f : b.h[5];
    b.h[6] = q3 ? (_Float16)0.0f : b.h[6];
    b.h[7] = q3 ? (_Float16)0.0f : b.h[7];
}

// ---------------- Stage 1: mean + segment embedding (monolithic) ------------
// Full static unroll (acc[] compile-time indexed — no scratch), 4 partial
// sums for the mean reduce. Writes mean-corrected seg_inT directly.
extern "C" __global__ __launch_bounds__(384)
void k_seg(const float* __restrict__ x, const float* __restrict__ seg,
           float* __restrict__ seg_inT, float* __restrict__ meanw) {
    const int b = blockIdx.x;
    const int c = threadIdx.x;
    if (c >= NC) return;
    float sw[NW];
#pragma unroll
    for (int w = 0; w < NW; ++w) sw[w] = seg[c * NW + w];
    float acc[NS];
    float s0 = 0.0f, s1 = 0.0f, s2 = 0.0f, s3 = 0.0f;
    const float* xb = x + (size_t)b * NL * NC + c;
#pragma unroll
    for (int s = 0; s < NS; ++s) {
        float a = 0.0f;
        float t0 = 0.0f, t1 = 0.0f, t2 = 0.0f, t3 = 0.0f;
#pragma unroll
        for (int w = 0; w < NW; w += 4) {
            const float v0 = xb[(s * NW + w) * NC];
            const float v1 = xb[(s * NW + w + 1) * NC];
            const float v2 = xb[(s * NW + w + 2) * NC];
            const float v3 = xb[(s * NW + w + 3) * NC];
            t0 += v0; t1 += v1; t2 += v2; t3 += v3;
            a = fmaf(v0, sw[w], a);
            a = fmaf(v1, sw[w + 1], a);
            a = fmaf(v2, sw[w + 2], a);
            a = fmaf(v3, sw[w + 3], a);
        }
        s0 += t0; s1 += t1; s2 += t2; s3 += t3;
        acc[s] = a;
    }
    const float mean = ((s0 + s1) + (s2 + s3)) * (1.0f / (float)NL);
    float ssum = 0.0f;
#pragma unroll
    for (int w = 0; w < NW; ++w) ssum += sw[w];
    meanw[b * NC + c] = mean;
#pragma unroll
    for (int s = 0; s < NS; ++s)
        seg_inT[((size_t)s * NC + c) * NB + b] = acc[s] - mean * ssum;
}

// ---------------- Stage 2: f16-MFMA LSTM, zero-LDS, reg-squeezed ------------
// Same math as R12 (best: 220 us) but MFMA->tail FUSED per mg: one live
// accumulator instead of 8 (the 3-phase split forced ~32 live acc regs ->
// AGPR alloc -> 128-reg quantum -> 16 waves/CU cap, the all-session
// occupancy plateau). launch_bounds(256,8) targets total <=64 regs ->
// 32 waves/CU. wpl packed f16 (2 regs); phn built in-loop (replaces hnv[8]).
extern "C" __global__ __launch_bounds__(256, 8)
void k_lstm(const float* __restrict__ seg_inT, const float* __restrict__ W_ih,
            const float* __restrict__ W_hh, const float* __restrict__ b_ih,
            const float* __restrict__ b_hh, const float* __restrict__ Wp,
            const float* __restrict__ bp, float* __restrict__ preds) {
    const int c = blockIdx.x;
    const int wv = threadIdx.x >> 6;
    const int lane = threadIdx.x & 63;
    const int b0 = (blockIdx.y * WPB + wv) * BSL;
    const int bb = lane & 15;         // column (batch) / A-row
    const int q  = lane >> 4;         // k-chunk / C row-quad
    const bool q3 = (q == 3);

    // ---- hoisted A-fragments from global (one-time, L2/L3-resident) ----
    const int qq = bb >> 2, rr = bb & 3;
    const float srow = (rr == 2) ? 2.88539008177792681472f : LOG2E;
    const float* __restrict__ whh = W_hh + (size_t)c * NG * NH;
    const float* __restrict__ wxp = W_ih + (size_t)c * NG;
    const float* __restrict__ bip = b_ih + (size_t)c * NG;
    const float* __restrict__ bhp = b_hh + (size_t)c * NG;
    F8 afr[8];
#pragma unroll 1
    for (int mg = 0; mg < 8; ++mg) {
        const int jj = qq * 8 + mg;
        const int grow = rr * NH + jj;
        F8 f0;
#pragma unroll
        for (int e = 0; e < 8; ++e) {
            const int k = q * 8 + e;
            float v0 = 0.0f;
            if (jj < NH) {
                if (k < NH)         v0 = whh[grow * NH + k] * srow;
                else if (k == 25)   v0 = wxp[grow] * srow;
                else if (k == 26)   v0 = (bip[grow] + bhp[grow]) * srow;
            }
            f0.h[e] = (_Float16)v0;
        }
        afr[mg] = f0;
    }

    // projection weights packed f16 (2 VGPRs instead of 8)
    F8 wph;
#pragma unroll
    for (int mg = 0; mg < 8; ++mg) {
        const int j = q * 8 + mg;
        wph.h[mg] = (_Float16)((j < NH) ? Wp[(size_t)c * NH + j] : 0.0f);
    }
    const float bpc = bp[c];

    // ---- initial B-fragment: h = 0, xt = seg_in[s=0] ----
    F8 ph;
    {
        const float x0 = seg_inT[(size_t)c * NB + b0 + bb];
#pragma unroll
        for (int e = 0; e < 8; ++e) ph.h[e] = (_Float16)0.0f;
        set_q3f(ph, q3, x0);
    }

    float cst[8];
#pragma unroll
    for (int mg = 0; mg < 8; ++mg) cst[mg] = 0.0f;

    // ---- recurrence: fused MFMA->tail per mg, one live accumulator ----
#pragma unroll 1
    for (int t = 0; t < NT; ++t) {
        const bool enc_next = (t + 1 < NS);
        const bool do_proj = (t >= NS - 1);
        const bool have_next = (t + 1 < NT);

        // prefetch next encoder input early (L2/L3-resident)
        float xn = 0.0f;
        if (enc_next)
            xn = seg_inT[((size_t)(t + 1) * NC + c) * NB + b0 + bb];

        F8 phn;
        float pp = 0.0f;
#pragma unroll
        for (int mg = 0; mg < 8; ++mg) {
            f32x4 z = {0.0f, 0.0f, 0.0f, 0.0f};
            const f32x4 a = __builtin_amdgcn_mfma_f32_16x16x32_f16(afr[mg].v, ph.v, z, 0, 0, 0);
            // regs: 0=i, 1=f, 2=g, 3=o of hidden j=8q+mg, batch bb (exp2 dom)
            const float ei = __builtin_amdgcn_exp2f(-a[0]);
            const float ef = __builtin_amdgcn_exp2f(-a[1]);
            const float eg = __builtin_amdgcn_exp2f(-a[2]);
            const float eo = __builtin_amdgcn_exp2f(-a[3]);
            const float p1f = 1.0f + ef;
            const float pig = (1.0f + ei) * (1.0f + eg);
            const float num = fmaf(cst[mg], pig, (1.0f - eg) * p1f);
            const float cn  = num * __builtin_amdgcn_rcpf(p1f * pig);
            const float et  = __builtin_amdgcn_exp2f(cn * N2LOG2E);
            const float hn  = (1.0f - et) *
                              __builtin_amdgcn_rcpf((1.0f + eo) * (1.0f + et));
            cst[mg] = cn;
            phn.h[mg] = (_Float16)hn;
            if (do_proj) pp = fmaf(hn, (float)wph.h[mg], pp);
        }

        float ov = 0.0f;
        if (do_proj) {
            pp += __shfl_xor(pp, 16);
            pp += __shfl_xor(pp, 32);
            ov = pp + bpc;
            if (q == 0)
                preds[((size_t)c * NP + (t - (NS - 1))) * NB + b0 + bb] = ov;
        }

        if (have_next) {
            set_q3f(phn, q3, enc_next ? xn : ov);
            ph = phn;
        }
    }
}

// ---------------- Stage 3: expand predictions to output ---------------------
extern "C" __global__ __launch_bounds__(384)
void k_out(const float* __restrict__ preds, const float* __restrict__ seg,
           const float* __restrict__ meanw, float* __restrict__ out) {
    const int b = blockIdx.x;
    const int p = blockIdx.y;
    const int c = threadIdx.x;
    if (c >= NC) return;
    const float pv = preds[((size_t)c * NP + p) * NB + b];
    const float mean = meanw[b * NC + c];
    float* ob = out + ((size_t)b * (NP * NW) + p * NW) * NC + c;
#pragma unroll
    for (int w = 0; w < NW; ++w)
        ob[w * NC] = fmaf(pv, seg[c * NW + w], mean);
}

extern "C" void kernel_launch(void* const* d_in, const int* in_sizes, int n_in,
                              void* d_out, int out_size, void* d_ws, size_t ws_size,
                              hipStream_t stream) {
    const float* x    = (const float*)d_in[0];
    const float* seg  = (const float*)d_in[1];
    const float* W_ih = (const float*)d_in[2];
    const float* W_hh = (const float*)d_in[3];
    const float* b_ih = (const float*)d_in[4];
    const float* b_hh = (const float*)d_in[5];
    const float* Wp   = (const float*)d_in[6];
    const float* bp   = (const float*)d_in[7];
    float* out = (float*)d_out;

    float* seg_inT = (float*)d_ws;                     // 28*321*512
    float* meanw   = seg_inT + (size_t)NS * NC * NB;   // 512*321
    float* preds   = meanw + (size_t)NB * NC;          // 321*8*512

    k_seg<<<NB, 384, 0, stream>>>(x, seg, seg_inT, meanw);
    k_lstm<<<dim3(NC, NB / (BSL * WPB)), 256, 0, stream>>>(
        seg_inT, W_ih, W_hh, b_ih, b_hh, Wp, bp, preds);
    k_out<<<dim3(NB, NP), 384, 0, stream>>>(preds, seg, meanw, out);
}

// Round 18
// 335.838 us; speedup vs baseline: 1.0846x; 1.0846x over previous
//
#include <hip/hip_runtime.h>
#include <math.h>

#define NB 512
#define NL 336
#define NC 321
#define NS 28
#define NW 12
#define NH 25
#define NP 8
#define NG 100
#define NT (NS + NP - 1)  // 35 cell steps
#define BSL 16            // batches per wave (1 MFMA column-tile)
#define WPB 4             // independent waves per 256-thread block
#define LOG2E 1.44269504088896340736f
#define N2LOG2E -2.88539008177792681472f

typedef __attribute__((ext_vector_type(8))) _Float16 f16x8;
typedef __attribute__((ext_vector_type(4))) float f32x4;

union F8 { f16x8 v; _Float16 h[8]; };

// q==3 lane carries the extra K-slots: k25=xt, k26=1.0 (A=bias row), k27..31=0
__device__ __forceinline__ void set_q3f(F8& b, bool q3, float xt) {
    b.h[1] = q3 ? (_Float16)xt : b.h[1];
    b.h[2] = q3 ? (_Float16)1.0f : b.h[2];
    b.h[3] = q3 ? (_Float16)0.0f : b.h[3];
    b.h[4] = q3 ? (_Float16)0.0f : b.h[4];
    b.h[5] = q3 ? (_Float16)0.0f : b.h[5];
    b.h[6] = q3 ? (_Float16)0.0f : b.h[6];
    b.h[7] = q3 ? (_Float16)0.0f : b.h[7];
}

// ---------------- Stage 1: mean + segment embedding (monolithic) ------------
extern "C" __global__ __launch_bounds__(384)
void k_seg(const float* __restrict__ x, const float* __restrict__ seg,
           float* __restrict__ seg_inT, float* __restrict__ meanw) {
    const int b = blockIdx.x;
    const int c = threadIdx.x;
    if (c >= NC) return;
    float sw[NW];
#pragma unroll
    for (int w = 0; w < NW; ++w) sw[w] = seg[c * NW + w];
    float acc[NS];
    float s0 = 0.0f, s1 = 0.0f, s2 = 0.0f, s3 = 0.0f;
    const float* xb = x + (size_t)b * NL * NC + c;
#pragma unroll
    for (int s = 0; s < NS; ++s) {
        float a = 0.0f;
        float t0 = 0.0f, t1 = 0.0f, t2 = 0.0f, t3 = 0.0f;
#pragma unroll
        for (int w = 0; w < NW; w += 4) {
            const float v0 = xb[(s * NW + w) * NC];
            const float v1 = xb[(s * NW + w + 1) * NC];
            const float v2 = xb[(s * NW + w + 2) * NC];
            const float v3 = xb[(s * NW + w + 3) * NC];
            t0 += v0; t1 += v1; t2 += v2; t3 += v3;
            a = fmaf(v0, sw[w], a);
            a = fmaf(v1, sw[w + 1], a);
            a = fmaf(v2, sw[w + 2], a);
            a = fmaf(v3, sw[w + 3], a);
        }
        s0 += t0; s1 += t1; s2 += t2; s3 += t3;
        acc[s] = a;
    }
    const float mean = ((s0 + s1) + (s2 + s3)) * (1.0f / (float)NL);
    float ssum = 0.0f;
#pragma unroll
    for (int w = 0; w < NW; ++w) ssum += sw[w];
    meanw[b * NC + c] = mean;
#pragma unroll
    for (int s = 0; s < NS; ++s)
        seg_inT[((size_t)s * NC + c) * NB + b] = acc[s] - mean * ssum;
}

// ---------------- Stage 2: f16-MFMA LSTM, zero-LDS recurrence ---------------
// R12 3-phase body (best measured), (256,4). t-loop split into a pure
// encoder loop (t=0..26: no proj/branches) and a decoder loop (t=27..34):
// removes per-iteration conditionals from 77% of the steps.
extern "C" __global__ __launch_bounds__(256, 4)
void k_lstm(const float* __restrict__ seg_inT, const float* __restrict__ W_ih,
            const float* __restrict__ W_hh, const float* __restrict__ b_ih,
            const float* __restrict__ b_hh, const float* __restrict__ Wp,
            const float* __restrict__ bp, float* __restrict__ preds) {
    const int c = blockIdx.x;
    const int wv = threadIdx.x >> 6;
    const int lane = threadIdx.x & 63;
    const int b0 = (blockIdx.y * WPB + wv) * BSL;
    const int bb = lane & 15;         // column (batch) / A-row
    const int q  = lane >> 4;         // k-chunk / C row-quad
    const bool q3 = (q == 3);

    // ---- hoisted A-fragments from global (one-time, L2/L3-resident) ----
    const int qq = bb >> 2, rr = bb & 3;
    const float srow = (rr == 2) ? 2.88539008177792681472f : LOG2E;
    const float* __restrict__ whh = W_hh + (size_t)c * NG * NH;
    const float* __restrict__ wxp = W_ih + (size_t)c * NG;
    const float* __restrict__ bip = b_ih + (size_t)c * NG;
    const float* __restrict__ bhp = b_hh + (size_t)c * NG;
    F8 afr[8];
#pragma unroll 1
    for (int mg = 0; mg < 8; ++mg) {
        const int jj = qq * 8 + mg;
        const int grow = rr * NH + jj;
        F8 f0;
#pragma unroll
        for (int e = 0; e < 8; ++e) {
            const int k = q * 8 + e;
            float v0 = 0.0f;
            if (jj < NH) {
                if (k < NH)         v0 = whh[grow * NH + k] * srow;
                else if (k == 25)   v0 = wxp[grow] * srow;
                else if (k == 26)   v0 = (bip[grow] + bhp[grow]) * srow;
            }
            f0.h[e] = (_Float16)v0;
        }
        afr[mg] = f0;
    }

    float wpl[8];
#pragma unroll
    for (int mg = 0; mg < 8; ++mg) {
        const int j = q * 8 + mg;
        wpl[mg] = (j < NH) ? Wp[(size_t)c * NH + j] : 0.0f;
    }
    const float bpc = bp[c];

    // ---- initial B-fragment: h = 0, xt = seg_in[s=0] ----
    F8 ph;
    {
        const float x0 = seg_inT[(size_t)c * NB + b0 + bb];
#pragma unroll
        for (int e = 0; e < 8; ++e) ph.h[e] = (_Float16)0.0f;
        set_q3f(ph, q3, x0);
    }

    float cst[8];
#pragma unroll
    for (int mg = 0; mg < 8; ++mg) cst[mg] = 0.0f;

    // ---- encoder loop: t = 0..NS-2, no projection, branch-free body ----
#pragma unroll 1
    for (int t = 0; t < NS - 1; ++t) {
        const float xn = seg_inT[((size_t)(t + 1) * NC + c) * NB + b0 + bb];

        f32x4 av[8];
#pragma unroll
        for (int mg = 0; mg < 8; ++mg) {
            f32x4 z = {0.0f, 0.0f, 0.0f, 0.0f};
            av[mg] = __builtin_amdgcn_mfma_f32_16x16x32_f16(afr[mg].v, ph.v, z, 0, 0, 0);
        }

        float ei[8], ef[8], eg[8], eo[8];
#pragma unroll
        for (int mg = 0; mg < 8; ++mg) {
            ei[mg] = __builtin_amdgcn_exp2f(-av[mg][0]);
            ef[mg] = __builtin_amdgcn_exp2f(-av[mg][1]);
            eg[mg] = __builtin_amdgcn_exp2f(-av[mg][2]);
            eo[mg] = __builtin_amdgcn_exp2f(-av[mg][3]);
        }

        F8 phn;
#pragma unroll
        for (int mg = 0; mg < 8; ++mg) {
            const float p1f = 1.0f + ef[mg];
            const float pig = (1.0f + ei[mg]) * (1.0f + eg[mg]);
            const float num = fmaf(cst[mg], pig, (1.0f - eg[mg]) * p1f);
            const float cn  = num * __builtin_amdgcn_rcpf(p1f * pig);
            const float et  = __builtin_amdgcn_exp2f(cn * N2LOG2E);
            const float hn  = (1.0f - et) *
                              __builtin_amdgcn_rcpf((1.0f + eo[mg]) * (1.0f + et));
            cst[mg] = cn;
            phn.h[mg] = (_Float16)hn;
        }
        set_q3f(phn, q3, xn);
        ph = phn;
    }

    // ---- decoder loop: t = NS-1..NT-1, projection every step ----
#pragma unroll 1
    for (int t = NS - 1; t < NT; ++t) {
        f32x4 av[8];
#pragma unroll
        for (int mg = 0; mg < 8; ++mg) {
            f32x4 z = {0.0f, 0.0f, 0.0f, 0.0f};
            av[mg] = __builtin_amdgcn_mfma_f32_16x16x32_f16(afr[mg].v, ph.v, z, 0, 0, 0);
        }

        float ei[8], ef[8], eg[8], eo[8];
#pragma unroll
        for (int mg = 0; mg < 8; ++mg) {
            ei[mg] = __builtin_amdgcn_exp2f(-av[mg][0]);
            ef[mg] = __builtin_amdgcn_exp2f(-av[mg][1]);
            eg[mg] = __builtin_amdgcn_exp2f(-av[mg][2]);
            eo[mg] = __builtin_amdgcn_exp2f(-av[mg][3]);
        }

        F8 phn;
        float pp = 0.0f;
#pragma unroll
        for (int mg = 0; mg < 8; ++mg) {
            const float p1f = 1.0f + ef[mg];
            const float pig = (1.0f + ei[mg]) * (1.0f + eg[mg]);
            const float num = fmaf(cst[mg], pig, (1.0f - eg[mg]) * p1f);
            const float cn  = num * __builtin_amdgcn_rcpf(p1f * pig);
            const float et  = __builtin_amdgcn_exp2f(cn * N2LOG2E);
            const float hn  = (1.0f - et) *
                              __builtin_amdgcn_rcpf((1.0f + eo[mg]) * (1.0f + et));
            cst[mg] = cn;
            phn.h[mg] = (_Float16)hn;
            pp = fmaf(hn, wpl[mg], pp);
        }

        pp += __shfl_xor(pp, 16);
        pp += __shfl_xor(pp, 32);
        const float ov = pp + bpc;
        if (q == 0)
            preds[((size_t)c * NP + (t - (NS - 1))) * NB + b0 + bb] = ov;

        if (t + 1 < NT) {
            set_q3f(phn, q3, ov);
            ph = phn;
        }
    }
}

// ---------------- Stage 3: expand predictions to output ---------------------
extern "C" __global__ __launch_bounds__(384)
void k_out(const float* __restrict__ preds, const float* __restrict__ seg,
           const float* __restrict__ meanw, float* __restrict__ out) {
    const int b = blockIdx.x;
    const int p = blockIdx.y;
    const int c = threadIdx.x;
    if (c >= NC) return;
    const float pv = preds[((size_t)c * NP + p) * NB + b];
    const float mean = meanw[b * NC + c];
    float* ob = out + ((size_t)b * (NP * NW) + p * NW) * NC + c;
#pragma unroll
    for (int w = 0; w < NW; ++w)
        ob[w * NC] = fmaf(pv, seg[c * NW + w], mean);
}

extern "C" void kernel_launch(void* const* d_in, const int* in_sizes, int n_in,
                              void* d_out, int out_size, void* d_ws, size_t ws_size,
                              hipStream_t stream) {
    const float* x    = (const float*)d_in[0];
    const float* seg  = (const float*)d_in[1];
    const float* W_ih = (const float*)d_in[2];
    const float* W_hh = (const float*)d_in[3];
    const float* b_ih = (const float*)d_in[4];
    const float* b_hh = (const float*)d_in[5];
    const float* Wp   = (const float*)d_in[6];
    const float* bp   = (const float*)d_in[7];
    float* out = (float*)d_out;

    float* seg_inT = (float*)d_ws;                     // 28*321*512
    float* meanw   = seg_inT + (size_t)NS * NC * NB;   // 512*321
    float* preds   = meanw + (size_t)NB * NC;          // 321*8*512

    k_seg<<<NB, 384, 0, stream>>>(x, seg, seg_inT, meanw);
    k_lstm<<<dim3(NC, NB / (BSL * WPB)), 256, 0, stream>>>(
        seg_inT, W_ih, W_hh, b_ih, b_hh, Wp, bp, preds);
    k_out<<<dim3(NB, NP), 384, 0, stream>>>(preds, seg, meanw, out);
}

// Round 19
// 281.059 us; speedup vs baseline: 1.2960x; 1.1949x over previous
//
#include <hip/hip_runtime.h>
#include <math.h>

#define NB 512
#define NL 336
#define NC 321
#define NS 28
#define NW 12
#define NH 25
#define NP 8
#define NG 100
#define NT (NS + NP - 1)  // 35 cell steps
#define BSL 16            // batches per wave (1 MFMA column-tile)
#define WPB 4             // independent waves per 256-thread block
#define LOG2E 1.44269504088896340736f
#define N2LOG2E -2.88539008177792681472f

typedef __attribute__((ext_vector_type(8))) _Float16 f16x8;
typedef __attribute__((ext_vector_type(4))) float f32x4;

union F8 { f16x8 v; _Float16 h[8]; };

// q==3 lane carries the extra K-slots: k25=xt, k26=1.0 (A=bias row), k27..31=0
__device__ __forceinline__ void set_q3f(F8& b, bool q3, float xt) {
    b.h[1] = q3 ? (_Float16)xt : b.h[1];
    b.h[2] = q3 ? (_Float16)1.0f : b.h[2];
    b.h[3] = q3 ? (_Float16)0.0f : b.h[3];
    b.h[4] = q3 ? (_Float16)0.0f : b.h[4];
    b.h[5] = q3 ? (_Float16)0.0f : b.h[5];
    b.h[6] = q3 ? (_Float16)0.0f : b.h[6];
    b.h[7] = q3 ? (_Float16)0.0f : b.h[7];
}

// ---------------- Stage 1: mean + segment embedding -------------------------
// seg_bc layout (s, b, c): thread c writes CONSECUTIVE addresses -> full
// coalesced lines, block-private (the old (s,c,b) layout scattered each
// wave-store over 64 lines shared across XCDs -> writeback amplification).
extern "C" __global__ __launch_bounds__(384)
void k_seg(const float* __restrict__ x, const float* __restrict__ seg,
           float* __restrict__ seg_bc, float* __restrict__ meanw) {
    const int b = blockIdx.x;
    const int c = threadIdx.x;
    if (c >= NC) return;
    float sw[NW];
#pragma unroll
    for (int w = 0; w < NW; ++w) sw[w] = seg[c * NW + w];
    float acc[NS];
    float s0 = 0.0f, s1 = 0.0f, s2 = 0.0f, s3 = 0.0f;
    const float* xb = x + (size_t)b * NL * NC + c;
#pragma unroll
    for (int s = 0; s < NS; ++s) {
        float a = 0.0f;
        float t0 = 0.0f, t1 = 0.0f, t2 = 0.0f, t3 = 0.0f;
#pragma unroll
        for (int w = 0; w < NW; w += 4) {
            const float v0 = xb[(s * NW + w) * NC];
            const float v1 = xb[(s * NW + w + 1) * NC];
            const float v2 = xb[(s * NW + w + 2) * NC];
            const float v3 = xb[(s * NW + w + 3) * NC];
            t0 += v0; t1 += v1; t2 += v2; t3 += v3;
            a = fmaf(v0, sw[w], a);
            a = fmaf(v1, sw[w + 1], a);
            a = fmaf(v2, sw[w + 2], a);
            a = fmaf(v3, sw[w + 3], a);
        }
        s0 += t0; s1 += t1; s2 += t2; s3 += t3;
        acc[s] = a;
    }
    const float mean = ((s0 + s1) + (s2 + s3)) * (1.0f / (float)NL);
    float ssum = 0.0f;
#pragma unroll
    for (int w = 0; w < NW; ++w) ssum += sw[w];
    meanw[b * NC + c] = mean;
#pragma unroll
    for (int s = 0; s < NS; ++s)
        seg_bc[((size_t)s * NB + b) * NC + c] = acc[s] - mean * ssum;
}

// ---------------- Stage 2: f16-MFMA LSTM, zero-LDS recurrence ---------------
// R18 body (best: 215.6 us). Grid swapped to (slabs, NC): a channel's 8
// slabs get consecutive block ids -> weights stay L2-hot (FETCH was 86 MB
// with (NC, slabs)). seg read is per-lane strided (16 lines/wave-load) but
// L2/L3-resident -> absorbed.
extern "C" __global__ __launch_bounds__(256, 4)
void k_lstm(const float* __restrict__ seg_bc, const float* __restrict__ W_ih,
            const float* __restrict__ W_hh, const float* __restrict__ b_ih,
            const float* __restrict__ b_hh, const float* __restrict__ Wp,
            const float* __restrict__ bp, float* __restrict__ preds) {
    const int c = blockIdx.y;
    const int wv = threadIdx.x >> 6;
    const int lane = threadIdx.x & 63;
    const int b0 = (blockIdx.x * WPB + wv) * BSL;
    const int bb = lane & 15;         // column (batch) / A-row
    const int q  = lane >> 4;         // k-chunk / C row-quad
    const bool q3 = (q == 3);

    // ---- hoisted A-fragments from global (one-time, L2-resident) ----
    const int qq = bb >> 2, rr = bb & 3;
    const float srow = (rr == 2) ? 2.88539008177792681472f : LOG2E;
    const float* __restrict__ whh = W_hh + (size_t)c * NG * NH;
    const float* __restrict__ wxp = W_ih + (size_t)c * NG;
    const float* __restrict__ bip = b_ih + (size_t)c * NG;
    const float* __restrict__ bhp = b_hh + (size_t)c * NG;
    F8 afr[8];
#pragma unroll 1
    for (int mg = 0; mg < 8; ++mg) {
        const int jj = qq * 8 + mg;
        const int grow = rr * NH + jj;
        F8 f0;
#pragma unroll
        for (int e = 0; e < 8; ++e) {
            const int k = q * 8 + e;
            float v0 = 0.0f;
            if (jj < NH) {
                if (k < NH)         v0 = whh[grow * NH + k] * srow;
                else if (k == 25)   v0 = wxp[grow] * srow;
                else if (k == 26)   v0 = (bip[grow] + bhp[grow]) * srow;
            }
            f0.h[e] = (_Float16)v0;
        }
        afr[mg] = f0;
    }

    float wpl[8];
#pragma unroll
    for (int mg = 0; mg < 8; ++mg) {
        const int j = q * 8 + mg;
        wpl[mg] = (j < NH) ? Wp[(size_t)c * NH + j] : 0.0f;
    }
    const float bpc = bp[c];

    // ---- initial B-fragment: h = 0, xt = seg_in[s=0] ----
    F8 ph;
    {
        const float x0 = seg_bc[((size_t)0 * NB + b0 + bb) * NC + c];
#pragma unroll
        for (int e = 0; e < 8; ++e) ph.h[e] = (_Float16)0.0f;
        set_q3f(ph, q3, x0);
    }

    float cst[8];
#pragma unroll
    for (int mg = 0; mg < 8; ++mg) cst[mg] = 0.0f;

    // ---- encoder loop: t = 0..NS-2, no projection, branch-free body ----
#pragma unroll 1
    for (int t = 0; t < NS - 1; ++t) {
        const float xn = seg_bc[((size_t)(t + 1) * NB + b0 + bb) * NC + c];

        f32x4 av[8];
#pragma unroll
        for (int mg = 0; mg < 8; ++mg) {
            f32x4 z = {0.0f, 0.0f, 0.0f, 0.0f};
            av[mg] = __builtin_amdgcn_mfma_f32_16x16x32_f16(afr[mg].v, ph.v, z, 0, 0, 0);
        }

        float ei[8], ef[8], eg[8], eo[8];
#pragma unroll
        for (int mg = 0; mg < 8; ++mg) {
            ei[mg] = __builtin_amdgcn_exp2f(-av[mg][0]);
            ef[mg] = __builtin_amdgcn_exp2f(-av[mg][1]);
            eg[mg] = __builtin_amdgcn_exp2f(-av[mg][2]);
            eo[mg] = __builtin_amdgcn_exp2f(-av[mg][3]);
        }

        F8 phn;
#pragma unroll
        for (int mg = 0; mg < 8; ++mg) {
            const float p1f = 1.0f + ef[mg];
            const float pig = (1.0f + ei[mg]) * (1.0f + eg[mg]);
            const float num = fmaf(cst[mg], pig, (1.0f - eg[mg]) * p1f);
            const float cn  = num * __builtin_amdgcn_rcpf(p1f * pig);
            const float et  = __builtin_amdgcn_exp2f(cn * N2LOG2E);
            const float hn  = (1.0f - et) *
                              __builtin_amdgcn_rcpf((1.0f + eo[mg]) * (1.0f + et));
            cst[mg] = cn;
            phn.h[mg] = (_Float16)hn;
        }
        set_q3f(phn, q3, xn);
        ph = phn;
    }

    // ---- decoder loop: t = NS-1..NT-1, projection every step ----
#pragma unroll 1
    for (int t = NS - 1; t < NT; ++t) {
        f32x4 av[8];
#pragma unroll
        for (int mg = 0; mg < 8; ++mg) {
            f32x4 z = {0.0f, 0.0f, 0.0f, 0.0f};
            av[mg] = __builtin_amdgcn_mfma_f32_16x16x32_f16(afr[mg].v, ph.v, z, 0, 0, 0);
        }

        float ei[8], ef[8], eg[8], eo[8];
#pragma unroll
        for (int mg = 0; mg < 8; ++mg) {
            ei[mg] = __builtin_amdgcn_exp2f(-av[mg][0]);
            ef[mg] = __builtin_amdgcn_exp2f(-av[mg][1]);
            eg[mg] = __builtin_amdgcn_exp2f(-av[mg][2]);
            eo[mg] = __builtin_amdgcn_exp2f(-av[mg][3]);
        }

        F8 phn;
        float pp = 0.0f;
#pragma unroll
        for (int mg = 0; mg < 8; ++mg) {
            const float p1f = 1.0f + ef[mg];
            const float pig = (1.0f + ei[mg]) * (1.0f + eg[mg]);
            const float num = fmaf(cst[mg], pig, (1.0f - eg[mg]) * p1f);
            const float cn  = num * __builtin_amdgcn_rcpf(p1f * pig);
            const float et  = __builtin_amdgcn_exp2f(cn * N2LOG2E);
            const float hn  = (1.0f - et) *
                              __builtin_amdgcn_rcpf((1.0f + eo[mg]) * (1.0f + et));
            cst[mg] = cn;
            phn.h[mg] = (_Float16)hn;
            pp = fmaf(hn, wpl[mg], pp);
        }

        pp += __shfl_xor(pp, 16);
        pp += __shfl_xor(pp, 32);
        const float ov = pp + bpc;
        if (q == 0)
            preds[((size_t)c * NP + (t - (NS - 1))) * NB + b0 + bb] = ov;

        if (t + 1 < NT) {
            set_q3f(phn, q3, ov);
            ph = phn;
        }
    }
}

// ---------------- Stage 3: expand predictions to output ---------------------
extern "C" __global__ __launch_bounds__(384)
void k_out(const float* __restrict__ preds, const float* __restrict__ seg,
           const float* __restrict__ meanw, float* __restrict__ out) {
    const int b = blockIdx.x;
    const int p = blockIdx.y;
    const int c = threadIdx.x;
    if (c >= NC) return;
    const float pv = preds[((size_t)c * NP + p) * NB + b];
    const float mean = meanw[b * NC + c];
    float* ob = out + ((size_t)b * (NP * NW) + p * NW) * NC + c;
#pragma unroll
    for (int w = 0; w < NW; ++w)
        ob[w * NC] = fmaf(pv, seg[c * NW + w], mean);
}

extern "C" void kernel_launch(void* const* d_in, const int* in_sizes, int n_in,
                              void* d_out, int out_size, void* d_ws, size_t ws_size,
                              hipStream_t stream) {
    const float* x    = (const float*)d_in[0];
    const float* seg  = (const float*)d_in[1];
    const float* W_ih = (const float*)d_in[2];
    const float* W_hh = (const float*)d_in[3];
    const float* b_ih = (const float*)d_in[4];
    const float* b_hh = (const float*)d_in[5];
    const float* Wp   = (const float*)d_in[6];
    const float* bp   = (const float*)d_in[7];
    float* out = (float*)d_out;

    float* seg_bc = (float*)d_ws;                      // 28*512*321 (s,b,c)
    float* meanw  = seg_bc + (size_t)NS * NB * NC;     // 512*321
    float* preds  = meanw + (size_t)NB * NC;           // 321*8*512

    k_seg<<<NB, 384, 0, stream>>>(x, seg, seg_bc, meanw);
    k_lstm<<<dim3(NB / (BSL * WPB), NC), 256, 0, stream>>>(
        seg_bc, W_ih, W_hh, b_ih, b_hh, Wp, bp, preds);
    k_out<<<dim3(NB, NP), 384, 0, stream>>>(preds, seg, meanw, out);
}